// Round 5
// baseline (374.960 us; speedup 1.0000x reference)
//
#include <hip/hip_runtime.h>
#include <math.h>

#define BATCH 128
#define ACT 7
#define NC 100
#define CTXD 128
#define HID 512
#define QW 600               // q cols 600..699 of reference are exactly 0

typedef __attribute__((ext_vector_type(8))) __bf16 bf16x8;
typedef __attribute__((ext_vector_type(4))) float f32x4;
typedef __attribute__((ext_vector_type(4))) unsigned short u16x4;

__device__ __forceinline__ unsigned short f2bf(float f) {
    union { float f; unsigned int u; } v; v.f = f;
    unsigned int u = v.u;
    return (unsigned short)((u + 0x7fffu + ((u >> 16) & 1u)) >> 16);
}
__device__ __forceinline__ float bf2f(unsigned short h) {
    return __uint_as_float((unsigned int)h << 16);
}
__device__ __forceinline__ unsigned int pack2bf(float a, float b) {
    unsigned int ua = __float_as_uint(a) + 0x8000u;
    unsigned int ub = __float_as_uint(b) + 0x8000u;
    return (ua >> 16) | (ub & 0xffff0000u);
}

__device__ __forceinline__ void async16(const void* g, void* l) {
    __builtin_amdgcn_global_load_lds(
        (const __attribute__((address_space(1))) unsigned int*)(uintptr_t)g,
        (__attribute__((address_space(3))) unsigned int*)(unsigned int)(uintptr_t)l,
        16, 0, 0);
}

// ---------------- prep: obs cvt + 4 transpose families + vq ------------------
// [0,64): obs bf16 copy
// [64,3136): 32x32 transpose tiles for W1AT / W2T (512x512 each, 6+6)
// [3136,3520): W1CT transpose  (src [128][512] -> dst [512][128]), 6 x 64
// [3520,3904): W3T  transpose  (src [512][128] -> dst [128][512]), 6 x 64
// [3904,3916): vq[z][k] = W3[z+1][k][:]·Wp
__global__ void prep_kernel(const float* __restrict__ obs, const float* __restrict__ W1,
                            const float* __restrict__ W2, const float* __restrict__ W3,
                            const float* __restrict__ Wp,
                            unsigned short* __restrict__ obs_bf, unsigned short* __restrict__ W1AT,
                            unsigned short* __restrict__ W2T, unsigned short* __restrict__ W1CT,
                            unsigned short* __restrict__ W3T, float* __restrict__ vq) {
    const int bidx = blockIdx.x, tid = threadIdx.x;
    if (bidx < 64) {
        const int e = (bidx * 256 + tid) * 4;   // 65536 elems
        float4 v = *(const float4*)(obs + e);
        u16x4 o; o[0] = f2bf(v.x); o[1] = f2bf(v.y); o[2] = f2bf(v.z); o[3] = f2bf(v.w);
        *(u16x4*)(obs_bf + e) = o;
    } else if (bidx < 3904) {
        __shared__ float tile[32][33];
        const float* ip; unsigned short* op;
        int src_ld, dst_ld, r0, c0;
        if (bidx < 3136) {
            const int idx = bidx - 64;          // 0..3071: 512x512 transposes
            const int z = idx >> 8, rem = idx & 255;
            const int rb = rem & 15, cb = rem >> 4;
            if (z < 6) { ip = W1 + (size_t)(z + 1) * 328192; op = W1AT + (size_t)z * 262144; }
            else       { int i = z - 6; ip = W2 + (size_t)(i + 1) * 262144; op = W2T + (size_t)i * 262144; }
            src_ld = 512; dst_ld = 512; r0 = rb * 32; c0 = cb * 32;
        } else if (bidx < 3520) {
            const int idx = bidx - 3136;        // 0..383: W1C [128][512] -> W1CT [512][128]
            const int i = idx >> 6, t = idx & 63;
            ip = W1 + (size_t)(i + 1) * 328192 + 513 * 512;
            op = W1CT + (size_t)i * 65536;
            src_ld = 512; dst_ld = 128; r0 = (t & 3) * 32; c0 = (t >> 2) * 32;
        } else {
            const int idx = bidx - 3520;        // 0..383: W3 [512][128] -> W3T [128][512]
            const int i = idx >> 6, t = idx & 63;
            ip = W3 + (size_t)(i + 1) * 65536;
            op = W3T + (size_t)i * 65536;
            src_ld = 128; dst_ld = 512; r0 = (t & 15) * 32; c0 = (t >> 4) * 32;
        }
        const int tx = tid & 31, ty = tid >> 5;  // 32 x 8
        #pragma unroll
        for (int j = 0; j < 32; j += 8)
            tile[ty + j][tx] = ip[(size_t)(r0 + ty + j) * src_ld + c0 + tx];
        __syncthreads();
        #pragma unroll
        for (int j = 0; j < 32; j += 8)
            op[(size_t)(c0 + ty + j) * dst_ld + r0 + tx] = f2bf(tile[tx][ty + j]);
    } else {
        const int idx = bidx - 3904;            // 0..11
        const int z = idx >> 1, k = (idx & 1) * 256 + tid;
        const float4* row = (const float4*)(W3 + (size_t)(z + 1) * 65536 + (size_t)k * 128);
        const float4* wp4 = (const float4*)Wp;
        float s = 0.f;
        #pragma unroll 8
        for (int n = 0; n < 32; ++n) {
            float4 a = row[n], w = wp4[n];
            s += a.x*w.x + a.y*w.y + a.z*w.z + a.w*w.w;
        }
        vq[z * 512 + k] = s;
    }
}

// ---------------- Yobs[z][b][h] = obs@W1A[z+1] + b1[z+1] ---------------------
__launch_bounds__(256)
__global__ void yobs_kernel(const unsigned short* __restrict__ A,      // obs_bf [128][512]
                            const unsigned short* __restrict__ BtAll,  // W1AT [6][512][512]
                            const float* __restrict__ b1,
                            float* __restrict__ Yobs) {
    __shared__ unsigned short As[64*32];
    __shared__ unsigned short Bs[128*32];
    const int m0 = blockIdx.x * 64;
    const int n0 = blockIdx.y * 128;
    const int z  = blockIdx.z;
    const unsigned short* Bt = BtAll + (size_t)z * 262144;
    const int tid = threadIdx.x, lane = tid & 63, wave = tid >> 6;
    const int wm = wave >> 1, wn = wave & 1;
    const int srow = tid >> 2, skc = (tid & 3) * 8;
    const unsigned short* gA  = A  + (size_t)(m0 + srow) * HID + skc;
    const unsigned short* gB0 = Bt + (size_t)(n0 + srow) * HID + skc;
    const unsigned short* gB1 = gB0 + 64 * HID;
    f32x4 acc[2][4] = {};
    for (int k0 = 0; k0 < HID; k0 += 32) {
        async16(gA + k0, As + tid*8);
        async16(gB0 + k0, Bs + tid*8);
        async16(gB1 + k0, Bs + 2048 + tid*8);
        __syncthreads();
        const int q8 = (lane >> 4) * 8, l15 = lane & 15;
        bf16x8 af[2], bfr[4];
        #pragma unroll
        for (int mt = 0; mt < 2; ++mt)
            af[mt] = *(const bf16x8*)(As + (wm*32 + mt*16 + l15) * 32 + q8);
        #pragma unroll
        for (int nt = 0; nt < 4; ++nt)
            bfr[nt] = *(const bf16x8*)(Bs + (wn*64 + nt*16 + l15) * 32 + q8);
        #pragma unroll
        for (int mt = 0; mt < 2; ++mt)
            #pragma unroll
            for (int nt = 0; nt < 4; ++nt)
                acc[mt][nt] = __builtin_amdgcn_mfma_f32_16x16x32_bf16(af[mt], bfr[nt], acc[mt][nt], 0, 0, 0);
        __syncthreads();
    }
    const int colL = wn*64 + (lane & 15);
    #pragma unroll
    for (int nt = 0; nt < 4; ++nt) {
        const int col = n0 + colL + nt*16;
        const float bb = b1[(z + 1) * HID + col];
        #pragma unroll
        for (int mt = 0; mt < 2; ++mt)
            #pragma unroll
            for (int r = 0; r < 4; ++r) {
                const int row = m0 + wm*32 + mt*16 + (lane >> 4)*4 + r;
                Yobs[(size_t)z * 65536 + (size_t)row * HID + col] = acc[mt][nt][r] + bb;
            }
    }
}

// ---------------- chain: MFMA-batched context chain (8 blocks x 16 b) --------
// Each block owns 16 b's for all 6 steps; layers are M=16 GEMMs via
// mfma_f32_16x16x32_bf16. Activations in LDS as compensated bf16 hi+lo
// (x ~ hi+lo to 2^-16): each product = 2 MFMAs -> precision matches the old
// f32(act)*bf16(w) path. B-fragments stream per-lane from transposed weights
// (W1CT/W2T/W3T: lane reads WT[col][k..k+7] bf16x8, 4 gq-lanes coalesce 64B).
// Activation LDS XOR-swizzled at 16B units (u^(row&7)) -> 2-way reads (free).
__launch_bounds__(512)
__global__ void chain_kernel(const float* __restrict__ Yobs, const float* __restrict__ W1,
                             const unsigned short* __restrict__ W1CT,
                             const unsigned short* __restrict__ W2T,
                             const unsigned short* __restrict__ W3T,
                             const float* __restrict__ b2, const float* __restrict__ b3,
                             const float* __restrict__ actions,
                             const float* __restrict__ Wp, const float* __restrict__ bp,
                             float* __restrict__ Y0all, float* __restrict__ QOFF) {
    __shared__ unsigned short ctxh[16*128], ctxl[16*128];   // 4KB + 4KB
    __shared__ unsigned short Ah[16*512], Al[16*512];       // 16KB + 16KB (h1)
    __shared__ unsigned short Bh[16*512], Bl[16*512];       // 16KB + 16KB (h2)
    __shared__ float wps[128];
    __shared__ float fjs[16];
    const int b0 = blockIdx.x * 16;
    const int tid = threadIdx.x, lane = tid & 63, wave = tid >> 6;
    const int l15 = lane & 15, gq = lane >> 4;
    for (int t2 = tid; t2 < 2048; t2 += 512) { ctxh[t2] = 0; ctxl[t2] = 0; }
    if (tid < 128) wps[tid] = Wp[tid];
    __syncthreads();

    for (int i = 1; i <= 6; ++i) {
        // ---- fjs + QOFF (from pre-step ctx) ----
        if (tid < 16) {
            float a = actions[(b0 + tid) * ACT + i];
            float fj = floorf((a + 1.0f) * 50.0f);
            fjs[tid] = fminf(fmaxf(fj, 0.0f), 99.0f);
        }
        {
            const int bl = wave * 2 + (lane >> 5);       // 0..15
            const int c0 = (lane & 31) * 4;
            float p = 0.f;
            #pragma unroll
            for (int j = 0; j < 4; ++j) {
                const int c = c0 + j;
                const int ad = bl * 128 + (((c >> 3) ^ (bl & 7)) << 3) + (c & 7);
                const float cv = bf2f(ctxh[ad]) + bf2f(ctxl[ad]);
                p += (cv + b3[i * 128 + c]) * wps[c];
            }
            p += __shfl_xor(p, 1, 64);  p += __shfl_xor(p, 2, 64);
            p += __shfl_xor(p, 4, 64);  p += __shfl_xor(p, 8, 64);
            p += __shfl_xor(p, 16, 64);
            if ((lane & 31) == 0) QOFF[(i - 1) * 128 + b0 + bl] = p + bp[0];
        }
        __syncthreads();

        // ---- Layer1: [16x512] = ctx(16x128) @ W1C + Yobs (+action) ----
        const float* w1a = W1 + (size_t)i * 328192 + 262144;
        #pragma unroll
        for (int j = 0; j < 4; ++j) {
            const int n0c = (wave + 8 * j) * 16;
            f32x4 acc = {};
            const unsigned short* wt = W1CT + (size_t)(i - 1) * 65536 + (size_t)(n0c + l15) * 128;
            #pragma unroll
            for (int kt = 0; kt < 4; ++kt) {
                const int su = ((kt * 4 + gq) ^ (l15 & 7)) * 8;
                bf16x8 ah = *(const bf16x8*)(ctxh + l15 * 128 + su);
                bf16x8 al = *(const bf16x8*)(ctxl + l15 * 128 + su);
                bf16x8 bb = *(const bf16x8*)(wt + kt * 32 + gq * 8);
                acc = __builtin_amdgcn_mfma_f32_16x16x32_bf16(ah, bb, acc, 0, 0, 0);
                acc = __builtin_amdgcn_mfma_f32_16x16x32_bf16(al, bb, acc, 0, 0, 0);
            }
            const int col = n0c + l15;
            const float wcol = w1a[col];
            #pragma unroll
            for (int r = 0; r < 4; ++r) {
                const int row = gq * 4 + r;
                const size_t go = (size_t)(i - 1) * 65536 + (size_t)(b0 + row) * 512 + col;
                const float y0 = acc[r] + Yobs[go];
                Y0all[go] = y0;
                const float h = fmaxf(fmaf(fjs[row], wcol, y0), 0.f);
                const unsigned short hh = f2bf(h);
                const unsigned short hl = f2bf(h - bf2f(hh));
                const int ad = row * 512 + (((col >> 3) ^ (row & 7)) << 3) + (col & 7);
                Ah[ad] = hh; Al[ad] = hl;
            }
        }
        __syncthreads();

        // ---- Layer2: [16x512] = h1 @ W2, relu ----
        #pragma unroll
        for (int j = 0; j < 4; ++j) {
            const int n0c = (wave + 8 * j) * 16;
            f32x4 acc = {};
            const unsigned short* wt = W2T + (size_t)(i - 1) * 262144 + (size_t)(n0c + l15) * 512;
            #pragma unroll
            for (int kt = 0; kt < 16; ++kt) {
                const int su = ((kt * 4 + gq) ^ (l15 & 7)) * 8;
                bf16x8 ah = *(const bf16x8*)(Ah + l15 * 512 + su);
                bf16x8 al = *(const bf16x8*)(Al + l15 * 512 + su);
                bf16x8 bb = *(const bf16x8*)(wt + kt * 32 + gq * 8);
                acc = __builtin_amdgcn_mfma_f32_16x16x32_bf16(ah, bb, acc, 0, 0, 0);
                acc = __builtin_amdgcn_mfma_f32_16x16x32_bf16(al, bb, acc, 0, 0, 0);
            }
            const int col = n0c + l15;
            const float bcol = b2[i * 512 + col];
            #pragma unroll
            for (int r = 0; r < 4; ++r) {
                const int row = gq * 4 + r;
                const float h = fmaxf(acc[r] + bcol, 0.f);
                const unsigned short hh = f2bf(h);
                const unsigned short hl = f2bf(h - bf2f(hh));
                const int ad = row * 512 + (((col >> 3) ^ (row & 7)) << 3) + (col & 7);
                Bh[ad] = hh; Bl[ad] = hl;
            }
        }
        __syncthreads();

        // ---- Layer3: [16x128] = h2 @ W3 + b3 + ctx -> ctx ----
        {
            const int n0c = wave * 16;                   // 8 waves x 16 = 128 cols
            f32x4 acc = {};
            const unsigned short* wt = W3T + (size_t)(i - 1) * 65536 + (size_t)(n0c + l15) * 512;
            #pragma unroll
            for (int kt = 0; kt < 16; ++kt) {
                const int su = ((kt * 4 + gq) ^ (l15 & 7)) * 8;
                bf16x8 ah = *(const bf16x8*)(Bh + l15 * 512 + su);
                bf16x8 al = *(const bf16x8*)(Bl + l15 * 512 + su);
                bf16x8 bb = *(const bf16x8*)(wt + kt * 32 + gq * 8);
                acc = __builtin_amdgcn_mfma_f32_16x16x32_bf16(ah, bb, acc, 0, 0, 0);
                acc = __builtin_amdgcn_mfma_f32_16x16x32_bf16(al, bb, acc, 0, 0, 0);
            }
            const int col = n0c + l15;
            const float b3c = b3[i * 128 + col];
            #pragma unroll
            for (int r = 0; r < 4; ++r) {
                const int row = gq * 4 + r;
                const int ad = row * 128 + (((col >> 3) ^ (row & 7)) << 3) + (col & 7);
                const float co = bf2f(ctxh[ad]) + bf2f(ctxl[ad]);
                const float cn = acc[r] + b3c + co;
                const unsigned short ch = f2bf(cn);
                ctxh[ad] = ch;
                ctxl[ad] = f2bf(cn - bf2f(ch));
            }
        }
        __syncthreads();
    }
}

// ---------------- h1all: H1[row][k] = bf16(relu(Y0+c*w1a)), 76800 rows -------
__global__ void h1all_kernel(const float* __restrict__ Y0all, const float* __restrict__ W1,
                             unsigned short* __restrict__ H1) {
    const int t = blockIdx.x * 256 + threadIdx.x;   // 76800*64 threads
    const int row = t >> 6, kc = (t & 63) << 3;
    const int z = row / 12800, rr = row - z * 12800;
    const int b = rr / 100;
    const float c = (float)(rr - b * 100);
    const float* yp = Y0all + (size_t)z*65536 + (size_t)b*512 + kc;
    const float* wp = W1 + (size_t)(z+1)*328192 + 262144 + kc;
    float4 ya = *(const float4*)(yp), yb = *(const float4*)(yp + 4);
    float4 wa = *(const float4*)(wp), wb = *(const float4*)(wp + 4);
    uint4 o;
    o.x = pack2bf(fmaxf(fmaf(c, wa.x, ya.x), 0.f), fmaxf(fmaf(c, wa.y, ya.y), 0.f));
    o.y = pack2bf(fmaxf(fmaf(c, wa.z, ya.z), 0.f), fmaxf(fmaf(c, wa.w, ya.w), 0.f));
    o.z = pack2bf(fmaxf(fmaf(c, wb.x, yb.x), 0.f), fmaxf(fmaf(c, wb.y, yb.y), 0.f));
    o.w = pack2bf(fmaxf(fmaf(c, wb.z, yb.z), 0.f), fmaxf(fmaf(c, wb.w, yb.w), 0.f));
    *(uint4*)(H1 + (size_t)row * 512 + kc) = o;
}

// ---------------- gemm2q: XCD-swizzled LDS GEMM + v-dot epilogue -------------
// (round-0 measured-best variant: 64.8us)
__launch_bounds__(256)
__global__ void gemm2q_kernel(const unsigned short* __restrict__ H1,
                              const unsigned short* __restrict__ W2T,
                              const float* __restrict__ b2,
                              const float* __restrict__ vq, float* __restrict__ qpart) {
    __shared__ unsigned short As[2][4096];
    __shared__ unsigned short Bs[2][4096];
    const int bidx = blockIdx.x;             // 0..2399
    const int xcd = bidx & 7, seq = bidx >> 3;
    const int plane = seq & 3;
    const int rt = xcd * 75 + (seq >> 2);    // 0..599
    const int z  = rt / 100;
    const int r0 = rt * 128;                 // global row
    const int n0 = plane * 128;
    const int tid = threadIdx.x, lane = tid & 63, wave = tid >> 6;
    const int wm = wave >> 1, wn = wave & 1;
    const int srow = tid >> 2, skc = (tid & 3) * 8;
    const int l15 = lane & 15, q8 = (lane >> 4) * 8;
    const unsigned short* gA0 = H1 + (size_t)(r0 + srow)*512 + skc;
    const unsigned short* gA1 = gA0 + 64*512;
    const unsigned short* gB0 = W2T + (size_t)z*262144 + (size_t)(n0 + srow)*512 + skc;
    const unsigned short* gB1 = gB0 + 64*512;
    f32x4 acc[4][4] = {};
    for (int k0 = 0; k0 < 512; k0 += 64) {
        async16(gA0 + k0,      &As[0][tid*8]);
        async16(gA1 + k0,      &As[0][2048 + tid*8]);
        async16(gA0 + k0 + 32, &As[1][tid*8]);
        async16(gA1 + k0 + 32, &As[1][2048 + tid*8]);
        async16(gB0 + k0,      &Bs[0][tid*8]);
        async16(gB1 + k0,      &Bs[0][2048 + tid*8]);
        async16(gB0 + k0 + 32, &Bs[1][tid*8]);
        async16(gB1 + k0 + 32, &Bs[1][2048 + tid*8]);
        __syncthreads();
        #pragma unroll
        for (int h = 0; h < 2; ++h) {
            bf16x8 af[4], bfr[4];
            #pragma unroll
            for (int mt = 0; mt < 4; ++mt)
                af[mt] = *(const bf16x8*)(&As[h][(wm*64 + mt*16 + l15)*32 + q8]);
            #pragma unroll
            for (int nt = 0; nt < 4; ++nt)
                bfr[nt] = *(const bf16x8*)(&Bs[h][(wn*64 + nt*16 + l15)*32 + q8]);
            #pragma unroll
            for (int mt = 0; mt < 4; ++mt)
                #pragma unroll
                for (int nt = 0; nt < 4; ++nt)
                    acc[mt][nt] = __builtin_amdgcn_mfma_f32_16x16x32_bf16(af[mt], bfr[nt], acc[mt][nt], 0, 0, 0);
        }
        __syncthreads();
    }
    // epilogue: p = sum_nt relu(acc + b2[col]) * v[col]; reduce over l15; store
    float vb[4], bb[4];
    #pragma unroll
    for (int nt = 0; nt < 4; ++nt) {
        const int col = n0 + wn*64 + nt*16 + l15;
        bb[nt] = b2[(z+1)*512 + col];
        vb[nt] = vq[z*512 + col];
    }
    const int plane2 = plane * 2 + wn;       // 0..7
    const int gq = lane >> 4;
    #pragma unroll
    for (int mt = 0; mt < 4; ++mt)
        #pragma unroll
        for (int r = 0; r < 4; ++r) {
            float p = 0.f;
            #pragma unroll
            for (int nt = 0; nt < 4; ++nt)
                p = fmaf(fmaxf(acc[mt][nt][r] + bb[nt], 0.f), vb[nt], p);
            p += __shfl_xor(p, 1, 64);
            p += __shfl_xor(p, 2, 64);
            p += __shfl_xor(p, 4, 64);
            p += __shfl_xor(p, 8, 64);
            if (l15 == 0) {
                const int grow = r0 + wm*64 + mt*16 + gq*4 + r;
                qpart[(size_t)plane2 * 76800 + grow] = p;
            }
        }
}

// ---------------- lse: out[b] = logsumexp([q[b,0:600], zeros(100)]) ----------
__global__ void lse_kernel(const float* __restrict__ qpart, const float* __restrict__ QOFF,
                           float* __restrict__ out) {
    __shared__ float red[256];
    __shared__ float qs[QW];
    const int b = blockIdx.x, t = threadIdx.x;
    for (int k = t; k < QW; k += 256) {
        const int z = k / 100, gc = k - z * 100;
        const int grow = z * 12800 + b * 100 + gc;
        float s = QOFF[z * 128 + b];
        #pragma unroll
        for (int p = 0; p < 8; ++p) s += qpart[(size_t)p * 76800 + grow];
        qs[k] = s;
    }
    __syncthreads();
    float m = 0.0f;   // zero tail participates in the max
    for (int k = t; k < QW; k += 256) m = fmaxf(m, qs[k]);
    red[t] = m; __syncthreads();
    for (int s = 128; s > 0; s >>= 1) { if (t < s) red[t] = fmaxf(red[t], red[t+s]); __syncthreads(); }
    m = red[0]; __syncthreads();
    float sum = 0.0f;
    for (int k = t; k < QW; k += 256) sum += expf(qs[k] - m);
    red[t] = sum; __syncthreads();
    for (int s = 128; s > 0; s >>= 1) { if (t < s) red[t] += red[t+s]; __syncthreads(); }
    if (t == 0) out[b] = logf(red[0] + 100.0f * expf(-m)) + m;
}

extern "C" void kernel_launch(void* const* d_in, const int* in_sizes, int n_in,
                              void* d_out, int out_size, void* d_ws, size_t ws_size,
                              hipStream_t stream) {
    const float* obs     = (const float*)d_in[0];
    const float* actions = (const float*)d_in[1];
    const float* W1      = (const float*)d_in[2];
    const float* b1      = (const float*)d_in[3];
    const float* W2      = (const float*)d_in[4];
    const float* b2      = (const float*)d_in[5];
    const float* W3      = (const float*)d_in[6];
    const float* b3      = (const float*)d_in[7];
    const float* Wp      = (const float*)d_in[8];
    const float* bp      = (const float*)d_in[9];
    float* out = (float*)d_out;
    float* ws  = (float*)d_ws;

    // workspace layout (float offsets)
    unsigned short* obs_bf = (unsigned short*)(ws);            // 32768 f
    unsigned short* W1AT   = (unsigned short*)(ws + 32768);    // 786432 f
    unsigned short* W2T    = (unsigned short*)(ws + 819200);   // 786432 f
    unsigned short* W1CT   = (unsigned short*)(ws + 1605632);  // 196608 f
    unsigned short* W3T    = (unsigned short*)(ws + 1802240);  // 196608 f
    float* Yobs  = ws + 1998848;                               // 393216 f
    float* Y0all = ws + 2392064;                               // 393216 f
    float* QOFF  = ws + 2785280;                               // 1024 f
    float* vq    = ws + 2786304;                               // 3072 f
    float* qpart = ws + 2789376;                               // 614400 f
    unsigned short* H1 = (unsigned short*)(ws + 3403776);      // 19660800 f

    prep_kernel<<<3916, 256, 0, stream>>>(obs, W1, W2, W3, Wp,
                                          obs_bf, W1AT, W2T, W1CT, W3T, vq);
    yobs_kernel<<<dim3(2,4,6), 256, 0, stream>>>(obs_bf, W1AT, b1, Yobs);
    chain_kernel<<<8, 512, 0, stream>>>(Yobs, W1, W1CT, W2T, W3T, b2, b3, actions, Wp, bp, Y0all, QOFF);
    h1all_kernel<<<19200, 256, 0, stream>>>(Y0all, W1, H1);
    gemm2q_kernel<<<2400, 256, 0, stream>>>(H1, W2T, b2, vq, qpart);
    lse_kernel<<<BATCH, 256, 0, stream>>>(qpart, QOFF, out);
}

// Round 6
// 265.864 us; speedup vs baseline: 1.4103x; 1.4103x over previous
//
#include <hip/hip_runtime.h>
#include <math.h>

#define BATCH 128
#define ACT 7
#define NC 100
#define CTXD 128
#define HID 512
#define QW 600               // q cols 600..699 of reference are exactly 0

typedef __attribute__((ext_vector_type(8))) __bf16 bf16x8;
typedef __attribute__((ext_vector_type(4))) float f32x4;
typedef __attribute__((ext_vector_type(4))) unsigned short u16x4;

__device__ __forceinline__ unsigned short f2bf(float f) {
    union { float f; unsigned int u; } v; v.f = f;
    unsigned int u = v.u;
    return (unsigned short)((u + 0x7fffu + ((u >> 16) & 1u)) >> 16);
}
__device__ __forceinline__ unsigned int pack2bf(float a, float b) {
    unsigned int ua = __float_as_uint(a) + 0x8000u;
    unsigned int ub = __float_as_uint(b) + 0x8000u;
    return (ua >> 16) | (ub & 0xffff0000u);
}

__device__ __forceinline__ void async16(const void* g, void* l) {
    __builtin_amdgcn_global_load_lds(
        (const __attribute__((address_space(1))) unsigned int*)(uintptr_t)g,
        (__attribute__((address_space(3))) unsigned int*)(unsigned int)(uintptr_t)l,
        16, 0, 0);
}

// ---------------- prep: cvt copies + transposes + vq in ONE launch -----------
// (round-0 proven version)
__global__ void prep_kernel(const float* __restrict__ obs, const float* __restrict__ W1,
                            const float* __restrict__ W2, const float* __restrict__ W3,
                            const float* __restrict__ Wp,
                            unsigned short* __restrict__ obs_bf, unsigned short* __restrict__ W1Cbf,
                            unsigned short* __restrict__ W2bf, unsigned short* __restrict__ W3bf,
                            unsigned short* __restrict__ W1AT, unsigned short* __restrict__ W2T,
                            float* __restrict__ vq) {
    const int bidx = blockIdx.x, tid = threadIdx.x;
    if (bidx < 2368) {
        const int e = (bidx * 256 + tid) * 4;   // 2424832 elems
        const float* src; unsigned short* dst;
        if (e < 65536)        { src = obs + e; dst = obs_bf + e; }
        else if (e < 458752)  { int f = e - 65536; int i = f >> 16; int rem = f & 65535;
                                src = W1 + (size_t)(i + 1) * 328192 + 513*512 + rem; dst = W1Cbf + f; }
        else if (e < 2031616) { int f = e - 458752; src = W2 + 262144 + f; dst = W2bf + f; }
        else                  { int f = e - 2031616; src = W3 + 65536 + f; dst = W3bf + f; }
        float4 v = *(const float4*)src;
        u16x4 o; o[0] = f2bf(v.x); o[1] = f2bf(v.y); o[2] = f2bf(v.z); o[3] = f2bf(v.w);
        *(u16x4*)dst = o;
    } else if (bidx < 5440) {
        __shared__ float tile[32][33];
        const int idx = bidx - 2368;            // 0..3071
        const int z = idx >> 8, rem = idx & 255;
        const int rb = rem & 15, cb = rem >> 4;
        const float* ip; unsigned short* op;
        if (z < 6) { ip = W1 + (size_t)(z + 1) * 328192; op = W1AT + (size_t)z * 262144; }
        else       { int i = z - 6; ip = W2 + (size_t)(i + 1) * 262144; op = W2T + (size_t)i * 262144; }
        const int r0 = rb * 32, c0 = cb * 32;
        const int tx = tid & 31, ty = tid >> 5;  // 32 x 8
        #pragma unroll
        for (int j = 0; j < 32; j += 8)
            tile[ty + j][tx] = ip[(size_t)(r0 + ty + j) * 512 + c0 + tx];
        __syncthreads();
        #pragma unroll
        for (int j = 0; j < 32; j += 8)
            op[(size_t)(c0 + ty + j) * 512 + r0 + tx] = f2bf(tile[tx][ty + j]);
    } else {
        const int idx = bidx - 5440;            // 0..11
        const int z = idx >> 1, k = (idx & 1) * 256 + tid;
        const float4* row = (const float4*)(W3 + (size_t)(z + 1) * 65536 + (size_t)k * 128);
        const float4* wp4 = (const float4*)Wp;
        float s = 0.f;
        #pragma unroll 8
        for (int n = 0; n < 32; ++n) {
            float4 a = row[n], w = wp4[n];
            s += a.x*w.x + a.y*w.y + a.z*w.z + a.w*w.w;
        }
        vq[z * 512 + k] = s;
    }
}

// ---------------- Yobs[z][b][h] = obs@W1A[z+1] + b1[z+1] ---------------------
__launch_bounds__(256)
__global__ void yobs_kernel(const unsigned short* __restrict__ A,      // obs_bf [128][512]
                            const unsigned short* __restrict__ BtAll,  // W1AT [6][512][512]
                            const float* __restrict__ b1,
                            float* __restrict__ Yobs) {
    __shared__ unsigned short As[64*32];
    __shared__ unsigned short Bs[128*32];
    const int m0 = blockIdx.x * 64;
    const int n0 = blockIdx.y * 128;
    const int z  = blockIdx.z;
    const unsigned short* Bt = BtAll + (size_t)z * 262144;
    const int tid = threadIdx.x, lane = tid & 63, wave = tid >> 6;
    const int wm = wave >> 1, wn = wave & 1;
    const int srow = tid >> 2, skc = (tid & 3) * 8;
    const unsigned short* gA  = A  + (size_t)(m0 + srow) * HID + skc;
    const unsigned short* gB0 = Bt + (size_t)(n0 + srow) * HID + skc;
    const unsigned short* gB1 = gB0 + 64 * HID;
    f32x4 acc[2][4] = {};
    for (int k0 = 0; k0 < HID; k0 += 32) {
        async16(gA + k0, As + tid*8);
        async16(gB0 + k0, Bs + tid*8);
        async16(gB1 + k0, Bs + 2048 + tid*8);
        __syncthreads();
        const int q8 = (lane >> 4) * 8, l15 = lane & 15;
        bf16x8 af[2], bfr[4];
        #pragma unroll
        for (int mt = 0; mt < 2; ++mt)
            af[mt] = *(const bf16x8*)(As + (wm*32 + mt*16 + l15) * 32 + q8);
        #pragma unroll
        for (int nt = 0; nt < 4; ++nt)
            bfr[nt] = *(const bf16x8*)(Bs + (wn*64 + nt*16 + l15) * 32 + q8);
        #pragma unroll
        for (int mt = 0; mt < 2; ++mt)
            #pragma unroll
            for (int nt = 0; nt < 4; ++nt)
                acc[mt][nt] = __builtin_amdgcn_mfma_f32_16x16x32_bf16(af[mt], bfr[nt], acc[mt][nt], 0, 0, 0);
        __syncthreads();
    }
    const int colL = wn*64 + (lane & 15);
    #pragma unroll
    for (int nt = 0; nt < 4; ++nt) {
        const int col = n0 + colL + nt*16;
        const float bb = b1[(z + 1) * HID + col];
        #pragma unroll
        for (int mt = 0; mt < 2; ++mt)
            #pragma unroll
            for (int r = 0; r < 4; ++r) {
                const int row = m0 + wm*32 + mt*16 + (lane >> 4)*4 + r;
                Yobs[(size_t)z * 65536 + (size_t)row * HID + col] = acc[mt][nt][r] + bb;
            }
    }
}

// ---------------- chain: serial context chain + QOFF precompute --------------
// (round-0 proven version: 128 blocks x 1024 threads, ~66us)
__launch_bounds__(1024)
__global__ void chain_kernel(const float* __restrict__ Yobs, const float* __restrict__ W1,
                             const unsigned short* __restrict__ W1Cbf,
                             const unsigned short* __restrict__ W2bf,
                             const unsigned short* __restrict__ W3bf,
                             const float* __restrict__ b2, const float* __restrict__ b3,
                             const float* __restrict__ actions,
                             const float* __restrict__ Wp, const float* __restrict__ bp,
                             float* __restrict__ Y0all, float* __restrict__ QOFF) {
    const int b = blockIdx.x, t = threadIdx.x;
    __shared__ float ctx[128], h1[512], h2s[512];
    __shared__ float part[2048];
    const int pair = t & 255, kq = t >> 8;
    const int pair3 = t & 63, kq3 = t >> 6;
    if (t < 128) ctx[t] = 0.f;
    __syncthreads();
    for (int i = 1; i <= 6; ++i) {
        if (t < 128) part[t] = (ctx[t] + b3[i*128 + t]) * Wp[t];
        __syncthreads();
        if (t < 64) {
            float v = part[t] + part[t + 64];
            #pragma unroll
            for (int o = 32; o > 0; o >>= 1) v += __shfl_down(v, o, 64);
            if (t == 0) QOFF[(i-1)*128 + b] = v + bp[0];
        }
        __syncthreads();
        const float a = actions[b*ACT + i];
        float fj = floorf((a + 1.0f) * 50.0f);
        fj = fminf(fmaxf(fj, 0.0f), 99.0f);
        // ---- layer1 ctx part ----
        {
            const unsigned int* wp1 = (const unsigned int*)(W1Cbf + (size_t)(i-1)*65536) + pair;
            float acc0 = 0.f, acc1 = 0.f;
            #pragma unroll 8
            for (int k = kq*32; k < kq*32 + 32; ++k) {
                unsigned int u = wp1[k*256];
                float c = ctx[k];
                acc0 = fmaf(c, __uint_as_float(u << 16), acc0);
                acc1 = fmaf(c, __uint_as_float(u & 0xffff0000u), acc1);
            }
            *(float2*)(&part[kq*512 + 2*pair]) = make_float2(acc0, acc1);
        }
        __syncthreads();
        if (t < 256) {
            const int n2 = 2*t;
            float2 p0 = *(const float2*)(&part[n2]);
            float2 p1 = *(const float2*)(&part[512 + n2]);
            float2 p2 = *(const float2*)(&part[1024 + n2]);
            float2 p3 = *(const float2*)(&part[1536 + n2]);
            float2 yo = *(const float2*)(Yobs + (size_t)(i-1)*65536 + b*512 + n2);
            float y0a = yo.x + p0.x + p1.x + p2.x + p3.x;
            float y0b = yo.y + p0.y + p1.y + p2.y + p3.y;
            *(float2*)(Y0all + (size_t)(i-1)*65536 + b*512 + n2) = make_float2(y0a, y0b);
            const float* w1a = W1 + (size_t)i*328192 + 262144;
            float2 wv = *(const float2*)(w1a + n2);
            h1[n2]   = fmaxf(fmaf(fj, wv.x, y0a), 0.f);
            h1[n2+1] = fmaxf(fmaf(fj, wv.y, y0b), 0.f);
        }
        __syncthreads();
        // ---- layer2 ----
        {
            const unsigned int* wp2 = (const unsigned int*)(W2bf + (size_t)(i-1)*262144) + pair;
            float acc0 = 0.f, acc1 = 0.f;
            #pragma unroll 16
            for (int k = kq*128; k < kq*128 + 128; ++k) {
                unsigned int u = wp2[k*256];
                float hv = h1[k];
                acc0 = fmaf(hv, __uint_as_float(u << 16), acc0);
                acc1 = fmaf(hv, __uint_as_float(u & 0xffff0000u), acc1);
            }
            *(float2*)(&part[kq*512 + 2*pair]) = make_float2(acc0, acc1);
        }
        __syncthreads();
        if (t < 256) {
            const int n2 = 2*t;
            float2 p0 = *(const float2*)(&part[n2]);
            float2 p1 = *(const float2*)(&part[512 + n2]);
            float2 p2 = *(const float2*)(&part[1024 + n2]);
            float2 p3 = *(const float2*)(&part[1536 + n2]);
            float2 bb = *(const float2*)(b2 + i*512 + n2);
            h2s[n2]   = fmaxf(p0.x + p1.x + p2.x + p3.x + bb.x, 0.f);
            h2s[n2+1] = fmaxf(p0.y + p1.y + p2.y + p3.y + bb.y, 0.f);
        }
        __syncthreads();
        // ---- layer3 ----
        {
            const unsigned int* wp3 = (const unsigned int*)(W3bf + (size_t)(i-1)*65536) + pair3;
            float acc0 = 0.f, acc1 = 0.f;
            #pragma unroll 8
            for (int k = kq3*32; k < kq3*32 + 32; ++k) {
                unsigned int u = wp3[k*64];
                float hv = h2s[k];
                acc0 = fmaf(hv, __uint_as_float(u << 16), acc0);
                acc1 = fmaf(hv, __uint_as_float(u & 0xffff0000u), acc1);
            }
            *(float2*)(&part[kq3*128 + 2*pair3]) = make_float2(acc0, acc1);
        }
        __syncthreads();
        if (t < 128) {
            float s = 0.f;
            #pragma unroll
            for (int qg = 0; qg < 16; ++qg) s += part[qg*128 + t];
            ctx[t] = s + b3[i*128 + t] + ctx[t];
        }
        __syncthreads();
    }
}

// ---------------- gemm2q: fused-A (h1all folded into A-staging) --------------
// r0 structure (proven fastest: 2400 blocks x 256 thr, 128x128 tile, XCD
// swizzle, 2-barrier K-loop) with ONE change: the A-tile is COMPUTED into
// LDS instead of async-loaded from the H1 intermediate.
//   A[row][k] = pack2bf(relu(fma(c, w1a[k], Y0all[z][b][k])))  (bit-identical
//   to the old h1all output). Sources are tiny and L2-resident: Y0all[z] =
//   256 KB (<=2 distinct b per tile -> loads broadcast), w1a = 2 KB.
// Thread (row=tid>>1, half=tid&1) computes 32 elems: 8 float4 L2 loads,
// ~50 VALU, 4 ds_write_b128 -- replacing 4 HBM-latency global_load_lds.
// Deletes the h1all kernel and all 78 MB of H1 traffic.
__launch_bounds__(256)
__global__ void gemm2q_kernel(const float* __restrict__ Y0all,
                              const float* __restrict__ W1,
                              const unsigned short* __restrict__ W2T,
                              const float* __restrict__ b2,
                              const float* __restrict__ vq, float* __restrict__ qpart) {
    __shared__ unsigned short As[2][4096];
    __shared__ unsigned short Bs[2][4096];
    const int bidx = blockIdx.x;             // 0..2399
    const int xcd = bidx & 7, seq = bidx >> 3;
    const int plane = seq & 3;
    const int rt = xcd * 75 + (seq >> 2);    // 0..599
    const int z  = rt / 100;
    const int r0 = rt * 128;                 // global row
    const int n0 = plane * 128;
    const int tid = threadIdx.x, lane = tid & 63, wave = tid >> 6;
    const int wm = wave >> 1, wn = wave & 1;
    const int srow = tid >> 2, skc = (tid & 3) * 8;
    const int l15 = lane & 15, q8 = (lane >> 4) * 8;
    // A-compute mapping: row ar = tid>>1 (0..127), half acg = tid&1 (k cols acg*32..+31)
    const int ar = tid >> 1, acg = tid & 1;
    const int zr = r0 + ar - z * 12800;      // row within z-block, 0..12799
    const int ab = zr / 100;                 // batch index
    const float ac = (float)(zr - 100 * ab); // component value c
    const float* ybase = Y0all + (size_t)z * 65536 + (size_t)ab * 512 + acg * 32;
    const float* wbase = W1 + (size_t)(z + 1) * 328192 + 262144 + acg * 32;
    unsigned short* adst = &As[acg][ar * 32];
    const unsigned short* gB0 = W2T + (size_t)z*262144 + (size_t)(n0 + srow)*512 + skc;
    const unsigned short* gB1 = gB0 + 64*512;
    f32x4 acc[4][4] = {};
    for (int k0 = 0; k0 < 512; k0 += 64) {
        async16(gB0 + k0,      &Bs[0][tid*8]);
        async16(gB1 + k0,      &Bs[0][2048 + tid*8]);
        async16(gB0 + k0 + 32, &Bs[1][tid*8]);
        async16(gB1 + k0 + 32, &Bs[1][2048 + tid*8]);
        // compute this K-tile's A half-row (32 elems) into LDS
        {
            const float* yp = ybase + k0;
            const float* wp = wbase + k0;
            #pragma unroll
            for (int j = 0; j < 4; ++j) {
                float4 ya = *(const float4*)(yp + j*8);
                float4 yb = *(const float4*)(yp + j*8 + 4);
                float4 wa = *(const float4*)(wp + j*8);
                float4 wb = *(const float4*)(wp + j*8 + 4);
                uint4 o;
                o.x = pack2bf(fmaxf(fmaf(ac, wa.x, ya.x), 0.f), fmaxf(fmaf(ac, wa.y, ya.y), 0.f));
                o.y = pack2bf(fmaxf(fmaf(ac, wa.z, ya.z), 0.f), fmaxf(fmaf(ac, wa.w, ya.w), 0.f));
                o.z = pack2bf(fmaxf(fmaf(ac, wb.x, yb.x), 0.f), fmaxf(fmaf(ac, wb.y, yb.y), 0.f));
                o.w = pack2bf(fmaxf(fmaf(ac, wb.z, yb.z), 0.f), fmaxf(fmaf(ac, wb.w, yb.w), 0.f));
                *(uint4*)(adst + j * 8) = o;
            }
        }
        __syncthreads();
        #pragma unroll
        for (int h = 0; h < 2; ++h) {
            bf16x8 af[4], bfr[4];
            #pragma unroll
            for (int mt = 0; mt < 4; ++mt)
                af[mt] = *(const bf16x8*)(&As[h][(wm*64 + mt*16 + l15)*32 + q8]);
            #pragma unroll
            for (int nt = 0; nt < 4; ++nt)
                bfr[nt] = *(const bf16x8*)(&Bs[h][(wn*64 + nt*16 + l15)*32 + q8]);
            #pragma unroll
            for (int mt = 0; mt < 4; ++mt)
                #pragma unroll
                for (int nt = 0; nt < 4; ++nt)
                    acc[mt][nt] = __builtin_amdgcn_mfma_f32_16x16x32_bf16(af[mt], bfr[nt], acc[mt][nt], 0, 0, 0);
        }
        __syncthreads();
    }
    // epilogue: p = sum_nt relu(acc + b2[col]) * v[col]; reduce over l15; store
    float vb[4], bb[4];
    #pragma unroll
    for (int nt = 0; nt < 4; ++nt) {
        const int col = n0 + wn*64 + nt*16 + l15;
        bb[nt] = b2[(z+1)*512 + col];
        vb[nt] = vq[z*512 + col];
    }
    const int plane2 = plane * 2 + wn;       // 0..7
    const int gq = lane >> 4;
    #pragma unroll
    for (int mt = 0; mt < 4; ++mt)
        #pragma unroll
        for (int r = 0; r < 4; ++r) {
            float p = 0.f;
            #pragma unroll
            for (int nt = 0; nt < 4; ++nt)
                p = fmaf(fmaxf(acc[mt][nt][r] + bb[nt], 0.f), vb[nt], p);
            p += __shfl_xor(p, 1, 64);
            p += __shfl_xor(p, 2, 64);
            p += __shfl_xor(p, 4, 64);
            p += __shfl_xor(p, 8, 64);
            if (l15 == 0) {
                const int grow = r0 + wm*64 + mt*16 + gq*4 + r;
                qpart[(size_t)plane2 * 76800 + grow] = p;
            }
        }
}

// ---------------- lse: out[b] = logsumexp([q[b,0:600], zeros(100)]) ----------
__global__ void lse_kernel(const float* __restrict__ qpart, const float* __restrict__ QOFF,
                           float* __restrict__ out) {
    __shared__ float red[256];
    __shared__ float qs[QW];
    const int b = blockIdx.x, t = threadIdx.x;
    for (int k = t; k < QW; k += 256) {
        const int z = k / 100, gc = k - z * 100;
        const int grow = z * 12800 + b * 100 + gc;
        float s = QOFF[z * 128 + b];
        #pragma unroll
        for (int p = 0; p < 8; ++p) s += qpart[(size_t)p * 76800 + grow];
        qs[k] = s;
    }
    __syncthreads();
    float m = 0.0f;   // zero tail participates in the max
    for (int k = t; k < QW; k += 256) m = fmaxf(m, qs[k]);
    red[t] = m; __syncthreads();
    for (int s = 128; s > 0; s >>= 1) { if (t < s) red[t] = fmaxf(red[t], red[t+s]); __syncthreads(); }
    m = red[0]; __syncthreads();
    float sum = 0.0f;
    for (int k = t; k < QW; k += 256) sum += expf(qs[k] - m);
    red[t] = sum; __syncthreads();
    for (int s = 128; s > 0; s >>= 1) { if (t < s) red[t] += red[t+s]; __syncthreads(); }
    if (t == 0) out[b] = logf(red[0] + 100.0f * expf(-m)) + m;
}

extern "C" void kernel_launch(void* const* d_in, const int* in_sizes, int n_in,
                              void* d_out, int out_size, void* d_ws, size_t ws_size,
                              hipStream_t stream) {
    const float* obs     = (const float*)d_in[0];
    const float* actions = (const float*)d_in[1];
    const float* W1      = (const float*)d_in[2];
    const float* b1      = (const float*)d_in[3];
    const float* W2      = (const float*)d_in[4];
    const float* b2      = (const float*)d_in[5];
    const float* W3      = (const float*)d_in[6];
    const float* b3      = (const float*)d_in[7];
    const float* Wp      = (const float*)d_in[8];
    const float* bp      = (const float*)d_in[9];
    float* out = (float*)d_out;
    float* ws  = (float*)d_ws;

    // workspace layout (float offsets)
    unsigned short* obs_bf = (unsigned short*)(ws);            // 32768 f
    unsigned short* W1AT   = (unsigned short*)(ws + 32768);    // 786432 f
    unsigned short* W2T    = (unsigned short*)(ws + 819200);   // 786432 f
    unsigned short* W1Cbf  = (unsigned short*)(ws + 1605632);  // 196608 f
    unsigned short* W2bf   = (unsigned short*)(ws + 1802240);  // 786432 f
    unsigned short* W3bf   = (unsigned short*)(ws + 2588672);  // 196608 f
    float* Yobs  = ws + 2785280;                               // 393216 f
    float* Y0all = ws + 3178496;                               // 393216 f
    float* QOFF  = ws + 3571712;                               // 1024 f
    float* vq    = ws + 3572736;                               // 3072 f
    float* qpart = ws + 3575808;                               // 614400 f

    prep_kernel<<<5452, 256, 0, stream>>>(obs, W1, W2, W3, Wp,
                                          obs_bf, W1Cbf, W2bf, W3bf, W1AT, W2T, vq);
    yobs_kernel<<<dim3(2,4,6), 256, 0, stream>>>(obs_bf, W1AT, b1, Yobs);
    chain_kernel<<<BATCH, 1024, 0, stream>>>(Yobs, W1, W1Cbf, W2bf, W3bf, b2, b3, actions, Wp, bp, Y0all, QOFF);
    gemm2q_kernel<<<2400, 256, 0, stream>>>(Y0all, W1, W2T, b2, vq, qpart);
    lse_kernel<<<BATCH, 256, 0, stream>>>(qpart, QOFF, out);
}

// Round 7
// 241.267 us; speedup vs baseline: 1.5541x; 1.1019x over previous
//
#include <hip/hip_runtime.h>
#include <math.h>

#define BATCH 128
#define ACT 7
#define NC 100
#define CTXD 128
#define HID 512
#define QW 600               // q cols 600..699 of reference are exactly 0

typedef __attribute__((ext_vector_type(8))) __bf16 bf16x8;
typedef __attribute__((ext_vector_type(4))) float f32x4;
typedef __attribute__((ext_vector_type(4))) unsigned short u16x4;

__device__ __forceinline__ unsigned short f2bf(float f) {
    union { float f; unsigned int u; } v; v.f = f;
    unsigned int u = v.u;
    return (unsigned short)((u + 0x7fffu + ((u >> 16) & 1u)) >> 16);
}
__device__ __forceinline__ unsigned int pack2bf(float a, float b) {
    unsigned int ua = __float_as_uint(a) + 0x8000u;
    unsigned int ub = __float_as_uint(b) + 0x8000u;
    return (ua >> 16) | (ub & 0xffff0000u);
}

__device__ __forceinline__ void async16(const void* g, void* l) {
    __builtin_amdgcn_global_load_lds(
        (const __attribute__((address_space(1))) unsigned int*)(uintptr_t)g,
        (__attribute__((address_space(3))) unsigned int*)(unsigned int)(uintptr_t)l,
        16, 0, 0);
}

// barrier macros for the chain pipeline (rule #18: sched_barrier fences)
#define BAR_LG() do { __builtin_amdgcn_sched_barrier(0); \
    asm volatile("s_waitcnt lgkmcnt(0)" ::: "memory"); \
    __builtin_amdgcn_s_barrier(); \
    __builtin_amdgcn_sched_barrier(0); } while (0)
#define BAR_VL() do { __builtin_amdgcn_sched_barrier(0); \
    asm volatile("s_waitcnt vmcnt(2) lgkmcnt(0)" ::: "memory"); \
    __builtin_amdgcn_s_barrier(); \
    __builtin_amdgcn_sched_barrier(0); } while (0)
#define BAR_V2() do { __builtin_amdgcn_sched_barrier(0); \
    asm volatile("s_waitcnt vmcnt(2)" ::: "memory"); \
    __builtin_amdgcn_s_barrier(); \
    __builtin_amdgcn_sched_barrier(0); } while (0)
#define BAR_V0() do { __builtin_amdgcn_sched_barrier(0); \
    asm volatile("s_waitcnt vmcnt(0)" ::: "memory"); \
    __builtin_amdgcn_s_barrier(); \
    __builtin_amdgcn_sched_barrier(0); } while (0)

// ---------------- prep: cvt copies + transposes + vq in ONE launch -----------
// (round-0 proven version)
__global__ void prep_kernel(const float* __restrict__ obs, const float* __restrict__ W1,
                            const float* __restrict__ W2, const float* __restrict__ W3,
                            const float* __restrict__ Wp,
                            unsigned short* __restrict__ obs_bf, unsigned short* __restrict__ W1Cbf,
                            unsigned short* __restrict__ W2bf, unsigned short* __restrict__ W3bf,
                            unsigned short* __restrict__ W1AT, unsigned short* __restrict__ W2T,
                            float* __restrict__ vq) {
    const int bidx = blockIdx.x, tid = threadIdx.x;
    if (bidx < 2368) {
        const int e = (bidx * 256 + tid) * 4;   // 2424832 elems
        const float* src; unsigned short* dst;
        if (e < 65536)        { src = obs + e; dst = obs_bf + e; }
        else if (e < 458752)  { int f = e - 65536; int i = f >> 16; int rem = f & 65535;
                                src = W1 + (size_t)(i + 1) * 328192 + 513*512 + rem; dst = W1Cbf + f; }
        else if (e < 2031616) { int f = e - 458752; src = W2 + 262144 + f; dst = W2bf + f; }
        else                  { int f = e - 2031616; src = W3 + 65536 + f; dst = W3bf + f; }
        float4 v = *(const float4*)src;
        u16x4 o; o[0] = f2bf(v.x); o[1] = f2bf(v.y); o[2] = f2bf(v.z); o[3] = f2bf(v.w);
        *(u16x4*)dst = o;
    } else if (bidx < 5440) {
        __shared__ float tile[32][33];
        const int idx = bidx - 2368;            // 0..3071
        const int z = idx >> 8, rem = idx & 255;
        const int rb = rem & 15, cb = rem >> 4;
        const float* ip; unsigned short* op;
        if (z < 6) { ip = W1 + (size_t)(z + 1) * 328192; op = W1AT + (size_t)z * 262144; }
        else       { int i = z - 6; ip = W2 + (size_t)(i + 1) * 262144; op = W2T + (size_t)i * 262144; }
        const int r0 = rb * 32, c0 = cb * 32;
        const int tx = tid & 31, ty = tid >> 5;  // 32 x 8
        #pragma unroll
        for (int j = 0; j < 32; j += 8)
            tile[ty + j][tx] = ip[(size_t)(r0 + ty + j) * 512 + c0 + tx];
        __syncthreads();
        #pragma unroll
        for (int j = 0; j < 32; j += 8)
            op[(size_t)(c0 + ty + j) * 512 + r0 + tx] = f2bf(tile[tx][ty + j]);
    } else {
        const int idx = bidx - 5440;            // 0..11
        const int z = idx >> 1, k = (idx & 1) * 256 + tid;
        const float4* row = (const float4*)(W3 + (size_t)(z + 1) * 65536 + (size_t)k * 128);
        const float4* wp4 = (const float4*)Wp;
        float s = 0.f;
        #pragma unroll 8
        for (int n = 0; n < 32; ++n) {
            float4 a = row[n], w = wp4[n];
            s += a.x*w.x + a.y*w.y + a.z*w.z + a.w*w.w;
        }
        vq[z * 512 + k] = s;
    }
}

// ---------------- Yobs[z][b][h] = obs@W1A[z+1] + b1[z+1] ---------------------
__launch_bounds__(256)
__global__ void yobs_kernel(const unsigned short* __restrict__ A,      // obs_bf [128][512]
                            const unsigned short* __restrict__ BtAll,  // W1AT [6][512][512]
                            const float* __restrict__ b1,
                            float* __restrict__ Yobs) {
    __shared__ unsigned short As[64*32];
    __shared__ unsigned short Bs[128*32];
    const int m0 = blockIdx.x * 64;
    const int n0 = blockIdx.y * 128;
    const int z  = blockIdx.z;
    const unsigned short* Bt = BtAll + (size_t)z * 262144;
    const int tid = threadIdx.x, lane = tid & 63, wave = tid >> 6;
    const int wm = wave >> 1, wn = wave & 1;
    const int srow = tid >> 2, skc = (tid & 3) * 8;
    const unsigned short* gA  = A  + (size_t)(m0 + srow) * HID + skc;
    const unsigned short* gB0 = Bt + (size_t)(n0 + srow) * HID + skc;
    const unsigned short* gB1 = gB0 + 64 * HID;
    f32x4 acc[2][4] = {};
    for (int k0 = 0; k0 < HID; k0 += 32) {
        async16(gA + k0, As + tid*8);
        async16(gB0 + k0, Bs + tid*8);
        async16(gB1 + k0, Bs + 2048 + tid*8);
        __syncthreads();
        const int q8 = (lane >> 4) * 8, l15 = lane & 15;
        bf16x8 af[2], bfr[4];
        #pragma unroll
        for (int mt = 0; mt < 2; ++mt)
            af[mt] = *(const bf16x8*)(As + (wm*32 + mt*16 + l15) * 32 + q8);
        #pragma unroll
        for (int nt = 0; nt < 4; ++nt)
            bfr[nt] = *(const bf16x8*)(Bs + (wn*64 + nt*16 + l15) * 32 + q8);
        #pragma unroll
        for (int mt = 0; mt < 2; ++mt)
            #pragma unroll
            for (int nt = 0; nt < 4; ++nt)
                acc[mt][nt] = __builtin_amdgcn_mfma_f32_16x16x32_bf16(af[mt], bfr[nt], acc[mt][nt], 0, 0, 0);
        __syncthreads();
    }
    const int colL = wn*64 + (lane & 15);
    #pragma unroll
    for (int nt = 0; nt < 4; ++nt) {
        const int col = n0 + colL + nt*16;
        const float bb = b1[(z + 1) * HID + col];
        #pragma unroll
        for (int mt = 0; mt < 2; ++mt)
            #pragma unroll
            for (int r = 0; r < 4; ++r) {
                const int row = m0 + wm*32 + mt*16 + (lane >> 4)*4 + r;
                Yobs[(size_t)z * 65536 + (size_t)row * HID + col] = acc[mt][nt][r] + bb;
            }
    }
}

// ---------------- chain: DMA-staged weights, counted-vmcnt pipeline ----------
// Same 128-block x 1024-thread structure and identical math as the proven r0
// chain; ONE change: all weight reads (W1C 128KB + W2 512KB + W3 128KB per
// step) stream global->LDS via global_load_lds into a 4 x 32KB ring, 2-deep
// pipelined with counted vmcnt(2) + raw s_barrier. Chunk loops contain NO
// compiler vector-memory ops (weights + activations both in LDS), so the
// counts are exact; section boundaries (which do have compiler loads) use
// full lgkm barriers, and FIFO vmcnt retirement makes those loads guarantee
// older DMA chunks have landed. k-partition per partial-sum is re-chunked
// (same k-set per column overall; fp32 sum reorder only).
__launch_bounds__(1024)
__global__ void chain_kernel(const float* __restrict__ Yobs, const float* __restrict__ W1,
                             const unsigned short* __restrict__ W1Cbf,
                             const unsigned short* __restrict__ W2bf,
                             const unsigned short* __restrict__ W3bf,
                             const float* __restrict__ b2, const float* __restrict__ b3,
                             const float* __restrict__ actions,
                             const float* __restrict__ Wp, const float* __restrict__ bp,
                             float* __restrict__ Y0all, float* __restrict__ QOFF) {
    const int b = blockIdx.x, t = threadIdx.x;
    __shared__ float ctx[128], h1[512], h2s[512];
    __shared__ float part[2048];
    __shared__ __align__(16) unsigned short wbuf[4][16384];   // 4 x 32KB ring
    const int pair = t & 255, kq = t >> 8;
    const int pair3 = t & 63, kq3 = t >> 6;

#define STAGEW(srcsh, bufi) do {                                   \
    const unsigned short* s_ = (srcsh);                            \
    async16(s_ + (size_t)t * 8,          &wbuf[bufi][t * 8]);      \
    async16(s_ + (size_t)(1024 + t) * 8, &wbuf[bufi][(1024 + t) * 8]); \
} while (0)

#define L1_CHUNK(c) do {                                           \
    const unsigned int* wb_ = (const unsigned int*)wbuf[(c) & 3];  \
    _Pragma("unroll")                                              \
    for (int kk = 0; kk < 8; ++kk) {                               \
        const int kl = kq * 8 + kk;                                \
        unsigned int u = wb_[kl * 256 + pair];                     \
        float cv = ctx[(c) * 32 + kl];                             \
        acc0 = fmaf(cv, __uint_as_float(u << 16), acc0);           \
        acc1 = fmaf(cv, __uint_as_float(u & 0xffff0000u), acc1);   \
    } } while (0)

#define L2_CHUNK(c) do {                                           \
    const unsigned int* wb_ = (const unsigned int*)wbuf[(c) & 3];  \
    _Pragma("unroll")                                              \
    for (int kk = 0; kk < 8; ++kk) {                               \
        const int kl = kq * 8 + kk;                                \
        unsigned int u = wb_[kl * 256 + pair];                     \
        float hv = h1[(c) * 32 + kl];                              \
        acc0 = fmaf(hv, __uint_as_float(u << 16), acc0);           \
        acc1 = fmaf(hv, __uint_as_float(u & 0xffff0000u), acc1);   \
    } } while (0)

#define L3_CHUNK(c) do {                                           \
    const unsigned int* wb_ = (const unsigned int*)wbuf[(c) & 3];  \
    _Pragma("unroll")                                              \
    for (int kk = 0; kk < 8; ++kk) {                               \
        const int kl = kq3 * 8 + kk;                               \
        unsigned int u = wb_[kl * 64 + pair3];                     \
        float hv = h2s[(c) * 128 + kl];                            \
        acc0 = fmaf(hv, __uint_as_float(u << 16), acc0);           \
        acc1 = fmaf(hv, __uint_as_float(u & 0xffff0000u), acc1);   \
    } } while (0)

    // prologue: stage step-1 W1C chunks 0,1
    STAGEW(W1Cbf, 0);
    STAGEW(W1Cbf + 16384, 1);
    if (t < 128) ctx[t] = 0.f;
    BAR_LG();

    for (int i = 1; i <= 6; ++i) {
        const unsigned short* w1src = W1Cbf + (size_t)(i - 1) * 65536;
        const unsigned short* w2src = W2bf + (size_t)(i - 1) * 262144;
        const unsigned short* w3src = W3bf + (size_t)(i - 1) * 65536;

        // ---- QOFF ----
        if (t < 128) part[t] = (ctx[t] + b3[i*128 + t]) * Wp[t];
        BAR_LG();
        if (t < 64) {
            float v = part[t] + part[t + 64];
            #pragma unroll
            for (int o = 32; o > 0; o >>= 1) v += __shfl_down(v, o, 64);
            if (t == 0) QOFF[(i-1)*128 + b] = v + bp[0];
        }
        BAR_VL();   // pre-layer1: W1C[0] landed (vmcnt<=2 keeps W1C[1] in flight)
        const float a = actions[b*ACT + i];
        float fj = floorf((a + 1.0f) * 50.0f);
        fj = fminf(fmaxf(fj, 0.0f), 99.0f);

        // ---- layer1: ctx @ W1C, 4 chunks of 32 k ----
        {
            float acc0 = 0.f, acc1 = 0.f;
            STAGEW(w1src + 2*16384, 2);
            L1_CHUNK(0);
            BAR_V2();                       // retire W1C[1]
            STAGEW(w1src + 3*16384, 3);
            L1_CHUNK(1);
            BAR_V2();                       // retire W1C[2]
            L1_CHUNK(2);
            BAR_V0();                       // retire W1C[3]
            L1_CHUNK(3);
            *(float2*)(&part[kq*512 + 2*pair]) = make_float2(acc0, acc1);
        }
        // stage W2 chunks 0,1 (bufs 0,1 free: >=3 barriers since their reads)
        STAGEW(w2src, 0);
        STAGEW(w2src + 16384, 1);
        BAR_LG();                           // publish layer1 partials; DMA flies

        // ---- h1 section (compiler Yobs loads retire W2[0,1] for t<256) ----
        if (t < 256) {
            const int n2 = 2*t;
            float2 p0 = *(const float2*)(&part[n2]);
            float2 p1 = *(const float2*)(&part[512 + n2]);
            float2 p2 = *(const float2*)(&part[1024 + n2]);
            float2 p3 = *(const float2*)(&part[1536 + n2]);
            float2 yo = *(const float2*)(Yobs + (size_t)(i-1)*65536 + b*512 + n2);
            float y0a = yo.x + p0.x + p1.x + p2.x + p3.x;
            float y0b = yo.y + p0.y + p1.y + p2.y + p3.y;
            *(float2*)(Y0all + (size_t)(i-1)*65536 + b*512 + n2) = make_float2(y0a, y0b);
            const float* w1a = W1 + (size_t)i*328192 + 262144;
            float2 wv = *(const float2*)(w1a + n2);
            h1[n2]   = fmaxf(fmaf(fj, wv.x, y0a), 0.f);
            h1[n2+1] = fmaxf(fmaf(fj, wv.y, y0b), 0.f);
        }
        BAR_VL();   // pre-layer2: W2[0] landed for every wave

        // ---- layer2: h1 @ W2, 16 chunks of 32 k ----
        {
            float acc0 = 0.f, acc1 = 0.f;
            #pragma unroll
            for (int c = 0; c < 16; ++c) {
                if (c + 2 < 16) STAGEW(w2src + (size_t)(c + 2) * 16384, (c + 2) & 3);
                L2_CHUNK(c);
                if (c < 15) { if (c + 2 < 16) BAR_V2(); else BAR_V0(); }
            }
            *(float2*)(&part[kq*512 + 2*pair]) = make_float2(acc0, acc1);
        }
        STAGEW(w3src, 0);
        STAGEW(w3src + 16384, 1);
        BAR_LG();                           // publish layer2 partials

        // ---- h2 section (b2 loads retire W3[0,1] for t<256) ----
        if (t < 256) {
            const int n2 = 2*t;
            float2 p0 = *(const float2*)(&part[n2]);
            float2 p1 = *(const float2*)(&part[512 + n2]);
            float2 p2 = *(const float2*)(&part[1024 + n2]);
            float2 p3 = *(const float2*)(&part[1536 + n2]);
            float2 bb = *(const float2*)(b2 + i*512 + n2);
            h2s[n2]   = fmaxf(p0.x + p1.x + p2.x + p3.x + bb.x, 0.f);
            h2s[n2+1] = fmaxf(p0.y + p1.y + p2.y + p3.y + bb.y, 0.f);
        }
        BAR_VL();   // pre-layer3: W3[0] landed for every wave

        // ---- layer3: h2 @ W3, 4 chunks of 128 k ----
        {
            float acc0 = 0.f, acc1 = 0.f;
            STAGEW(w3src + 2*16384, 2);
            L3_CHUNK(0);
            BAR_V2();                       // retire W3[1]
            STAGEW(w3src + 3*16384, 3);
            L3_CHUNK(1);
            BAR_V2();                       // retire W3[2]
            L3_CHUNK(2);
            BAR_V0();                       // retire W3[3]
            L3_CHUNK(3);
            *(float2*)(&part[kq3*128 + 2*pair3]) = make_float2(acc0, acc1);
        }
        if (i < 6) {                        // stage next step's W1C[0,1]
            const unsigned short* wn = W1Cbf + (size_t)i * 65536;
            STAGEW(wn, 0);
            STAGEW(wn + 16384, 1);
        }
        BAR_LG();                           // publish layer3 partials

        // ---- ctx update ----
        if (t < 128) {
            float s = 0.f;
            #pragma unroll
            for (int qg = 0; qg < 16; ++qg) s += part[qg*128 + t];
            ctx[t] = s + b3[i*128 + t] + ctx[t];
        }
        BAR_LG();
    }
#undef STAGEW
#undef L1_CHUNK
#undef L2_CHUNK
#undef L3_CHUNK
}

// ---------------- h1all: H1[row][k] = bf16(relu(Y0+c*w1a)), 76800 rows -------
__global__ void h1all_kernel(const float* __restrict__ Y0all, const float* __restrict__ W1,
                             unsigned short* __restrict__ H1) {
    const int t = blockIdx.x * 256 + threadIdx.x;   // 76800*64 threads
    const int row = t >> 6, kc = (t & 63) << 3;
    const int z = row / 12800, rr = row - z * 12800;
    const int b = rr / 100;
    const float c = (float)(rr - b * 100);
    const float* yp = Y0all + (size_t)z*65536 + (size_t)b*512 + kc;
    const float* wp = W1 + (size_t)(z+1)*328192 + 262144 + kc;
    float4 ya = *(const float4*)(yp), yb = *(const float4*)(yp + 4);
    float4 wa = *(const float4*)(wp), wb = *(const float4*)(wp + 4);
    uint4 o;
    o.x = pack2bf(fmaxf(fmaf(c, wa.x, ya.x), 0.f), fmaxf(fmaf(c, wa.y, ya.y), 0.f));
    o.y = pack2bf(fmaxf(fmaf(c, wa.z, ya.z), 0.f), fmaxf(fmaf(c, wa.w, ya.w), 0.f));
    o.z = pack2bf(fmaxf(fmaf(c, wb.x, yb.x), 0.f), fmaxf(fmaf(c, wb.y, yb.y), 0.f));
    o.w = pack2bf(fmaxf(fmaf(c, wb.z, yb.z), 0.f), fmaxf(fmaf(c, wb.w, yb.w), 0.f));
    *(uint4*)(H1 + (size_t)row * 512 + kc) = o;
}

// ---------------- gemm2q: XCD-swizzled LDS GEMM + v-dot epilogue -------------
// (round-0 measured-best variant: 64.8us, restored verbatim)
__launch_bounds__(256)
__global__ void gemm2q_kernel(const unsigned short* __restrict__ H1,
                              const unsigned short* __restrict__ W2T,
                              const float* __restrict__ b2,
                              const float* __restrict__ vq, float* __restrict__ qpart) {
    __shared__ unsigned short As[2][4096];
    __shared__ unsigned short Bs[2][4096];
    const int bidx = blockIdx.x;             // 0..2399
    const int xcd = bidx & 7, seq = bidx >> 3;
    const int plane = seq & 3;
    const int rt = xcd * 75 + (seq >> 2);    // 0..599
    const int z  = rt / 100;
    const int r0 = rt * 128;                 // global row
    const int n0 = plane * 128;
    const int tid = threadIdx.x, lane = tid & 63, wave = tid >> 6;
    const int wm = wave >> 1, wn = wave & 1;
    const int srow = tid >> 2, skc = (tid & 3) * 8;
    const int l15 = lane & 15, q8 = (lane >> 4) * 8;
    const unsigned short* gA0 = H1 + (size_t)(r0 + srow)*512 + skc;
    const unsigned short* gA1 = gA0 + 64*512;
    const unsigned short* gB0 = W2T + (size_t)z*262144 + (size_t)(n0 + srow)*512 + skc;
    const unsigned short* gB1 = gB0 + 64*512;
    f32x4 acc[4][4] = {};
    for (int k0 = 0; k0 < 512; k0 += 64) {
        async16(gA0 + k0,      &As[0][tid*8]);
        async16(gA1 + k0,      &As[0][2048 + tid*8]);
        async16(gA0 + k0 + 32, &As[1][tid*8]);
        async16(gA1 + k0 + 32, &As[1][2048 + tid*8]);
        async16(gB0 + k0,      &Bs[0][tid*8]);
        async16(gB1 + k0,      &Bs[0][2048 + tid*8]);
        async16(gB0 + k0 + 32, &Bs[1][tid*8]);
        async16(gB1 + k0 + 32, &Bs[1][2048 + tid*8]);
        __syncthreads();
        #pragma unroll
        for (int h = 0; h < 2; ++h) {
            bf16x8 af[4], bfr[4];
            #pragma unroll
            for (int mt = 0; mt < 4; ++mt)
                af[mt] = *(const bf16x8*)(&As[h][(wm*64 + mt*16 + l15)*32 + q8]);
            #pragma unroll
            for (int nt = 0; nt < 4; ++nt)
                bfr[nt] = *(const bf16x8*)(&Bs[h][(wn*64 + nt*16 + l15)*32 + q8]);
            #pragma unroll
            for (int mt = 0; mt < 4; ++mt)
                #pragma unroll
                for (int nt = 0; nt < 4; ++nt)
                    acc[mt][nt] = __builtin_amdgcn_mfma_f32_16x16x32_bf16(af[mt], bfr[nt], acc[mt][nt], 0, 0, 0);
        }
        __syncthreads();
    }
    // epilogue: p = sum_nt relu(acc + b2[col]) * v[col]; reduce over l15; store
    float vb[4], bb[4];
    #pragma unroll
    for (int nt = 0; nt < 4; ++nt) {
        const int col = n0 + wn*64 + nt*16 + l15;
        bb[nt] = b2[(z+1)*512 + col];
        vb[nt] = vq[z*512 + col];
    }
    const int plane2 = plane * 2 + wn;       // 0..7
    const int gq = lane >> 4;
    #pragma unroll
    for (int mt = 0; mt < 4; ++mt)
        #pragma unroll
        for (int r = 0; r < 4; ++r) {
            float p = 0.f;
            #pragma unroll
            for (int nt = 0; nt < 4; ++nt)
                p = fmaf(fmaxf(acc[mt][nt][r] + bb[nt], 0.f), vb[nt], p);
            p += __shfl_xor(p, 1, 64);
            p += __shfl_xor(p, 2, 64);
            p += __shfl_xor(p, 4, 64);
            p += __shfl_xor(p, 8, 64);
            if (l15 == 0) {
                const int grow = r0 + wm*64 + mt*16 + gq*4 + r;
                qpart[(size_t)plane2 * 76800 + grow] = p;
            }
        }
}

// ---------------- lse: out[b] = logsumexp([q[b,0:600], zeros(100)]) ----------
__global__ void lse_kernel(const float* __restrict__ qpart, const float* __restrict__ QOFF,
                           float* __restrict__ out) {
    __shared__ float red[256];
    __shared__ float qs[QW];
    const int b = blockIdx.x, t = threadIdx.x;
    for (int k = t; k < QW; k += 256) {
        const int z = k / 100, gc = k - z * 100;
        const int grow = z * 12800 + b * 100 + gc;
        float s = QOFF[z * 128 + b];
        #pragma unroll
        for (int p = 0; p < 8; ++p) s += qpart[(size_t)p * 76800 + grow];
        qs[k] = s;
    }
    __syncthreads();
    float m = 0.0f;   // zero tail participates in the max
    for (int k = t; k < QW; k += 256) m = fmaxf(m, qs[k]);
    red[t] = m; __syncthreads();
    for (int s = 128; s > 0; s >>= 1) { if (t < s) red[t] = fmaxf(red[t], red[t+s]); __syncthreads(); }
    m = red[0]; __syncthreads();
    float sum = 0.0f;
    for (int k = t; k < QW; k += 256) sum += expf(qs[k] - m);
    red[t] = sum; __syncthreads();
    for (int s = 128; s > 0; s >>= 1) { if (t < s) red[t] += red[t+s]; __syncthreads(); }
    if (t == 0) out[b] = logf(red[0] + 100.0f * expf(-m)) + m;
}

extern "C" void kernel_launch(void* const* d_in, const int* in_sizes, int n_in,
                              void* d_out, int out_size, void* d_ws, size_t ws_size,
                              hipStream_t stream) {
    const float* obs     = (const float*)d_in[0];
    const float* actions = (const float*)d_in[1];
    const float* W1      = (const float*)d_in[2];
    const float* b1      = (const float*)d_in[3];
    const float* W2      = (const float*)d_in[4];
    const float* b2      = (const float*)d_in[5];
    const float* W3      = (const float*)d_in[6];
    const float* b3      = (const float*)d_in[7];
    const float* Wp      = (const float*)d_in[8];
    const float* bp      = (const float*)d_in[9];
    float* out = (float*)d_out;
    float* ws  = (float*)d_ws;

    // workspace layout (float offsets)
    unsigned short* obs_bf = (unsigned short*)(ws);            // 32768 f
    unsigned short* W1AT   = (unsigned short*)(ws + 32768);    // 786432 f
    unsigned short* W2T    = (unsigned short*)(ws + 819200);   // 786432 f
    unsigned short* W1Cbf  = (unsigned short*)(ws + 1605632);  // 196608 f
    unsigned short* W2bf   = (unsigned short*)(ws + 1802240);  // 786432 f
    unsigned short* W3bf   = (unsigned short*)(ws + 2588672);  // 196608 f
    float* Yobs  = ws + 2785280;                               // 393216 f
    float* Y0all = ws + 3178496;                               // 393216 f
    float* QOFF  = ws + 3571712;                               // 1024 f
    float* vq    = ws + 3572736;                               // 3072 f
    float* qpart = ws + 3575808;                               // 614400 f
    unsigned short* H1 = (unsigned short*)(ws + 4190208);      // 19660800 f

    prep_kernel<<<5452, 256, 0, stream>>>(obs, W1, W2, W3, Wp,
                                          obs_bf, W1Cbf, W2bf, W3bf, W1AT, W2T, vq);
    yobs_kernel<<<dim3(2,4,6), 256, 0, stream>>>(obs_bf, W1AT, b1, Yobs);
    chain_kernel<<<BATCH, 1024, 0, stream>>>(Yobs, W1, W1Cbf, W2bf, W3bf, b2, b3, actions, Wp, bp, Y0all, QOFF);
    h1all_kernel<<<19200, 256, 0, stream>>>(Y0all, W1, H1);
    gemm2q_kernel<<<2400, 256, 0, stream>>>(H1, W2T, b2, vq, qpart);
    lse_kernel<<<BATCH, 256, 0, stream>>>(qpart, QOFF, out);
}

// Round 9
// 234.961 us; speedup vs baseline: 1.5958x; 1.0268x over previous
//
#include <hip/hip_runtime.h>
#include <math.h>

#define BATCH 128
#define ACT 7
#define NC 100
#define CTXD 128
#define HID 512
#define QW 600               // q cols 600..699 of reference are exactly 0

typedef __attribute__((ext_vector_type(8))) __bf16 bf16x8;
typedef __attribute__((ext_vector_type(4))) float f32x4;
typedef __attribute__((ext_vector_type(4))) unsigned short u16x4;

__device__ __forceinline__ unsigned short f2bf(float f) {
    union { float f; unsigned int u; } v; v.f = f;
    unsigned int u = v.u;
    return (unsigned short)((u + 0x7fffu + ((u >> 16) & 1u)) >> 16);
}
__device__ __forceinline__ unsigned int pack2bf(float a, float b) {
    unsigned int ua = __float_as_uint(a) + 0x8000u;
    unsigned int ub = __float_as_uint(b) + 0x8000u;
    return (ua >> 16) | (ub & 0xffff0000u);
}

__device__ __forceinline__ void async16(const void* g, void* l) {
    __builtin_amdgcn_global_load_lds(
        (const __attribute__((address_space(1))) unsigned int*)(uintptr_t)g,
        (__attribute__((address_space(3))) unsigned int*)(unsigned int)(uintptr_t)l,
        16, 0, 0);
}

// ---------------- prep: cvt copies + transposes + vq in ONE launch -----------
// (round-0 proven version)
__global__ void prep_kernel(const float* __restrict__ obs, const float* __restrict__ W1,
                            const float* __restrict__ W2, const float* __restrict__ W3,
                            const float* __restrict__ Wp,
                            unsigned short* __restrict__ obs_bf, unsigned short* __restrict__ W1Cbf,
                            unsigned short* __restrict__ W2bf, unsigned short* __restrict__ W3bf,
                            unsigned short* __restrict__ W1AT, unsigned short* __restrict__ W2T,
                            float* __restrict__ vq) {
    const int bidx = blockIdx.x, tid = threadIdx.x;
    if (bidx < 2368) {
        const int e = (bidx * 256 + tid) * 4;   // 2424832 elems
        const float* src; unsigned short* dst;
        if (e < 65536)        { src = obs + e; dst = obs_bf + e; }
        else if (e < 458752)  { int f = e - 65536; int i = f >> 16; int rem = f & 65535;
                                src = W1 + (size_t)(i + 1) * 328192 + 513*512 + rem; dst = W1Cbf + f; }
        else if (e < 2031616) { int f = e - 458752; src = W2 + 262144 + f; dst = W2bf + f; }
        else                  { int f = e - 2031616; src = W3 + 65536 + f; dst = W3bf + f; }
        float4 v = *(const float4*)src;
        u16x4 o; o[0] = f2bf(v.x); o[1] = f2bf(v.y); o[2] = f2bf(v.z); o[3] = f2bf(v.w);
        *(u16x4*)dst = o;
    } else if (bidx < 5440) {
        __shared__ float tile[32][33];
        const int idx = bidx - 2368;            // 0..3071
        const int z = idx >> 8, rem = idx & 255;
        const int rb = rem & 15, cb = rem >> 4;
        const float* ip; unsigned short* op;
        if (z < 6) { ip = W1 + (size_t)(z + 1) * 328192; op = W1AT + (size_t)z * 262144; }
        else       { int i = z - 6; ip = W2 + (size_t)(i + 1) * 262144; op = W2T + (size_t)i * 262144; }
        const int r0 = rb * 32, c0 = cb * 32;
        const int tx = tid & 31, ty = tid >> 5;  // 32 x 8
        #pragma unroll
        for (int j = 0; j < 32; j += 8)
            tile[ty + j][tx] = ip[(size_t)(r0 + ty + j) * 512 + c0 + tx];
        __syncthreads();
        #pragma unroll
        for (int j = 0; j < 32; j += 8)
            op[(size_t)(c0 + ty + j) * 512 + r0 + tx] = f2bf(tile[tx][ty + j]);
    } else {
        const int idx = bidx - 5440;            // 0..11
        const int z = idx >> 1, k = (idx & 1) * 256 + tid;
        const float4* row = (const float4*)(W3 + (size_t)(z + 1) * 65536 + (size_t)k * 128);
        const float4* wp4 = (const float4*)Wp;
        float s = 0.f;
        #pragma unroll 8
        for (int n = 0; n < 32; ++n) {
            float4 a = row[n], w = wp4[n];
            s += a.x*w.x + a.y*w.y + a.z*w.z + a.w*w.w;
        }
        vq[z * 512 + k] = s;
    }
}

// ---------------- Yobs[z][b][h] = obs@W1A[z+1] + b1[z+1] ---------------------
__launch_bounds__(256)
__global__ void yobs_kernel(const unsigned short* __restrict__ A,      // obs_bf [128][512]
                            const unsigned short* __restrict__ BtAll,  // W1AT [6][512][512]
                            const float* __restrict__ b1,
                            float* __restrict__ Yobs) {
    __shared__ unsigned short As[64*32];
    __shared__ unsigned short Bs[128*32];
    const int m0 = blockIdx.x * 64;
    const int n0 = blockIdx.y * 128;
    const int z  = blockIdx.z;
    const unsigned short* Bt = BtAll + (size_t)z * 262144;
    const int tid = threadIdx.x, lane = tid & 63, wave = tid >> 6;
    const int wm = wave >> 1, wn = wave & 1;
    const int srow = tid >> 2, skc = (tid & 3) * 8;
    const unsigned short* gA  = A  + (size_t)(m0 + srow) * HID + skc;
    const unsigned short* gB0 = Bt + (size_t)(n0 + srow) * HID + skc;
    const unsigned short* gB1 = gB0 + 64 * HID;
    f32x4 acc[2][4] = {};
    for (int k0 = 0; k0 < HID; k0 += 32) {
        async16(gA + k0, As + tid*8);
        async16(gB0 + k0, Bs + tid*8);
        async16(gB1 + k0, Bs + 2048 + tid*8);
        __syncthreads();
        const int q8 = (lane >> 4) * 8, l15 = lane & 15;
        bf16x8 af[2], bfr[4];
        #pragma unroll
        for (int mt = 0; mt < 2; ++mt)
            af[mt] = *(const bf16x8*)(As + (wm*32 + mt*16 + l15) * 32 + q8);
        #pragma unroll
        for (int nt = 0; nt < 4; ++nt)
            bfr[nt] = *(const bf16x8*)(Bs + (wn*64 + nt*16 + l15) * 32 + q8);
        #pragma unroll
        for (int mt = 0; mt < 2; ++mt)
            #pragma unroll
            for (int nt = 0; nt < 4; ++nt)
                acc[mt][nt] = __builtin_amdgcn_mfma_f32_16x16x32_bf16(af[mt], bfr[nt], acc[mt][nt], 0, 0, 0);
        __syncthreads();
    }
    const int colL = wn*64 + (lane & 15);
    #pragma unroll
    for (int nt = 0; nt < 4; ++nt) {
        const int col = n0 + colL + nt*16;
        const float bb = b1[(z + 1) * HID + col];
        #pragma unroll
        for (int mt = 0; mt < 2; ++mt)
            #pragma unroll
            for (int r = 0; r < 4; ++r) {
                const int row = m0 + wm*32 + mt*16 + (lane >> 4)*4 + r;
                Yobs[(size_t)z * 65536 + (size_t)row * HID + col] = acc[mt][nt][r] + bb;
            }
    }
}

// ---------------- chain: serial context chain + QOFF + FUSED H1 expansion ----
// r0 structure (128 blocks x 1024 threads, ~66.5us) with the h1all kernel
// folded into the per-step epilogue: after y0 is computed, all 1024 threads
// expand the 100 candidate components c into H1 rows (bit-identical bytes to
// the old h1all: same pack2bf(relu(fma(c, w1a[col], y0)))). Y0all round-trip
// deleted (nothing else read it). Adds ~150 VALU/thread/step + 78.6MB writes
// spread over chain's runtime (chain is 4% HBM, 22% VALU -- headroom).
__launch_bounds__(1024)
__global__ void chain_kernel(const float* __restrict__ Yobs, const float* __restrict__ W1,
                             const unsigned short* __restrict__ W1Cbf,
                             const unsigned short* __restrict__ W2bf,
                             const unsigned short* __restrict__ W3bf,
                             const float* __restrict__ b2, const float* __restrict__ b3,
                             const float* __restrict__ actions,
                             const float* __restrict__ Wp, const float* __restrict__ bp,
                             unsigned short* __restrict__ H1, float* __restrict__ QOFF) {
    const int b = blockIdx.x, t = threadIdx.x;
    __shared__ float ctx[128], h1[512], h2s[512];
    __shared__ float part[2048];
    __shared__ float y0s[512], wvs[512];
    const int pair = t & 255, kq = t >> 8;
    const int pair3 = t & 63, kq3 = t >> 6;
    if (t < 128) ctx[t] = 0.f;
    __syncthreads();
    for (int i = 1; i <= 6; ++i) {
        if (t < 128) part[t] = (ctx[t] + b3[i*128 + t]) * Wp[t];
        __syncthreads();
        if (t < 64) {
            float v = part[t] + part[t + 64];
            #pragma unroll
            for (int o = 32; o > 0; o >>= 1) v += __shfl_down(v, o, 64);
            if (t == 0) QOFF[(i-1)*128 + b] = v + bp[0];
        }
        __syncthreads();
        const float a = actions[b*ACT + i];
        float fj = floorf((a + 1.0f) * 50.0f);
        fj = fminf(fmaxf(fj, 0.0f), 99.0f);
        // ---- layer1 ctx part ----
        {
            const unsigned int* wp1 = (const unsigned int*)(W1Cbf + (size_t)(i-1)*65536) + pair;
            float acc0 = 0.f, acc1 = 0.f;
            #pragma unroll 8
            for (int k = kq*32; k < kq*32 + 32; ++k) {
                unsigned int u = wp1[k*256];
                float c = ctx[k];
                acc0 = fmaf(c, __uint_as_float(u << 16), acc0);
                acc1 = fmaf(c, __uint_as_float(u & 0xffff0000u), acc1);
            }
            *(float2*)(&part[kq*512 + 2*pair]) = make_float2(acc0, acc1);
        }
        __syncthreads();
        if (t < 256) {
            const int n2 = 2*t;
            float2 p0 = *(const float2*)(&part[n2]);
            float2 p1 = *(const float2*)(&part[512 + n2]);
            float2 p2 = *(const float2*)(&part[1024 + n2]);
            float2 p3 = *(const float2*)(&part[1536 + n2]);
            float2 yo = *(const float2*)(Yobs + (size_t)(i-1)*65536 + b*512 + n2);
            float y0a = yo.x + p0.x + p1.x + p2.x + p3.x;
            float y0b = yo.y + p0.y + p1.y + p2.y + p3.y;
            *(float2*)(&y0s[n2]) = make_float2(y0a, y0b);
            const float* w1a = W1 + (size_t)i*328192 + 262144;
            float2 wv = *(const float2*)(w1a + n2);
            *(float2*)(&wvs[n2]) = wv;
            h1[n2]   = fmaxf(fmaf(fj, wv.x, y0a), 0.f);
            h1[n2+1] = fmaxf(fmaf(fj, wv.y, y0b), 0.f);
        }
        __syncthreads();
        // ---- fused h1all: expand 100 candidate components into H1 ----
        // (bit-identical to the old h1all kernel's bytes)
        {
            const int pr = t & 255, cg = t >> 8;   // 256 col-pairs x 4 c-groups
            const int n2 = 2 * pr;
            const float2 y0v = *(const float2*)(&y0s[n2]);
            const float2 wvv = *(const float2*)(&wvs[n2]);
            unsigned int* hbase = (unsigned int*)(H1
                + (size_t)((i - 1) * 12800 + b * 100) * 512) + pr;
            #pragma unroll 5
            for (int cc = 0; cc < 25; ++cc) {
                const int c = cg * 25 + cc;
                const float fc = (float)c;
                hbase[(size_t)c * 256] = pack2bf(
                    fmaxf(fmaf(fc, wvv.x, y0v.x), 0.f),
                    fmaxf(fmaf(fc, wvv.y, y0v.y), 0.f));
            }
        }
        // ---- layer2 ----
        {
            const unsigned int* wp2 = (const unsigned int*)(W2bf + (size_t)(i-1)*262144) + pair;
            float acc0 = 0.f, acc1 = 0.f;
            #pragma unroll 16
            for (int k = kq*128; k < kq*128 + 128; ++k) {
                unsigned int u = wp2[k*256];
                float hv = h1[k];
                acc0 = fmaf(hv, __uint_as_float(u << 16), acc0);
                acc1 = fmaf(hv, __uint_as_float(u & 0xffff0000u), acc1);
            }
            *(float2*)(&part[kq*512 + 2*pair]) = make_float2(acc0, acc1);
        }
        __syncthreads();
        if (t < 256) {
            const int n2 = 2*t;
            float2 p0 = *(const float2*)(&part[n2]);
            float2 p1 = *(const float2*)(&part[512 + n2]);
            float2 p2 = *(const float2*)(&part[1024 + n2]);
            float2 p3 = *(const float2*)(&part[1536 + n2]);
            float2 bb = *(const float2*)(b2 + i*512 + n2);
            h2s[n2]   = fmaxf(p0.x + p1.x + p2.x + p3.x + bb.x, 0.f);
            h2s[n2+1] = fmaxf(p0.y + p1.y + p2.y + p3.y + bb.y, 0.f);
        }
        __syncthreads();
        // ---- layer3 ----
        {
            const unsigned int* wp3 = (const unsigned int*)(W3bf + (size_t)(i-1)*65536) + pair3;
            float acc0 = 0.f, acc1 = 0.f;
            #pragma unroll 8
            for (int k = kq3*32; k < kq3*32 + 32; ++k) {
                unsigned int u = wp3[k*64];
                float hv = h2s[k];
                acc0 = fmaf(hv, __uint_as_float(u << 16), acc0);
                acc1 = fmaf(hv, __uint_as_float(u & 0xffff0000u), acc1);
            }
            *(float2*)(&part[kq3*128 + 2*pair3]) = make_float2(acc0, acc1);
        }
        __syncthreads();
        if (t < 128) {
            float s = 0.f;
            #pragma unroll
            for (int qg = 0; qg < 16; ++qg) s += part[qg*128 + t];
            ctx[t] = s + b3[i*128 + t] + ctx[t];
        }
        __syncthreads();
    }
}

// ---------------- gemm2q: XCD-swizzled LDS GEMM + v-dot epilogue -------------
// (round-0 measured-best variant: 64.8us, restored verbatim)
__launch_bounds__(256)
__global__ void gemm2q_kernel(const unsigned short* __restrict__ H1,
                              const unsigned short* __restrict__ W2T,
                              const float* __restrict__ b2,
                              const float* __restrict__ vq, float* __restrict__ qpart) {
    __shared__ unsigned short As[2][4096];
    __shared__ unsigned short Bs[2][4096];
    const int bidx = blockIdx.x;             // 0..2399
    const int xcd = bidx & 7, seq = bidx >> 3;
    const int plane = seq & 3;
    const int rt = xcd * 75 + (seq >> 2);    // 0..599
    const int z  = rt / 100;
    const int r0 = rt * 128;                 // global row
    const int n0 = plane * 128;
    const int tid = threadIdx.x, lane = tid & 63, wave = tid >> 6;
    const int wm = wave >> 1, wn = wave & 1;
    const int srow = tid >> 2, skc = (tid & 3) * 8;
    const int l15 = lane & 15, q8 = (lane >> 4) * 8;
    const unsigned short* gA0 = H1 + (size_t)(r0 + srow)*512 + skc;
    const unsigned short* gA1 = gA0 + 64*512;
    const unsigned short* gB0 = W2T + (size_t)z*262144 + (size_t)(n0 + srow)*512 + skc;
    const unsigned short* gB1 = gB0 + 64*512;
    f32x4 acc[4][4] = {};
    for (int k0 = 0; k0 < 512; k0 += 64) {
        async16(gA0 + k0,      &As[0][tid*8]);
        async16(gA1 + k0,      &As[0][2048 + tid*8]);
        async16(gA0 + k0 + 32, &As[1][tid*8]);
        async16(gA1 + k0 + 32, &As[1][2048 + tid*8]);
        async16(gB0 + k0,      &Bs[0][tid*8]);
        async16(gB1 + k0,      &Bs[0][2048 + tid*8]);
        async16(gB0 + k0 + 32, &Bs[1][tid*8]);
        async16(gB1 + k0 + 32, &Bs[1][2048 + tid*8]);
        __syncthreads();
        #pragma unroll
        for (int h = 0; h < 2; ++h) {
            bf16x8 af[4], bfr[4];
            #pragma unroll
            for (int mt = 0; mt < 4; ++mt)
                af[mt] = *(const bf16x8*)(&As[h][(wm*64 + mt*16 + l15)*32 + q8]);
            #pragma unroll
            for (int nt = 0; nt < 4; ++nt)
                bfr[nt] = *(const bf16x8*)(&Bs[h][(wn*64 + nt*16 + l15)*32 + q8]);
            #pragma unroll
            for (int mt = 0; mt < 4; ++mt)
                #pragma unroll
                for (int nt = 0; nt < 4; ++nt)
                    acc[mt][nt] = __builtin_amdgcn_mfma_f32_16x16x32_bf16(af[mt], bfr[nt], acc[mt][nt], 0, 0, 0);
        }
        __syncthreads();
    }
    // epilogue: p = sum_nt relu(acc + b2[col]) * v[col]; reduce over l15; store
    float vb[4], bb[4];
    #pragma unroll
    for (int nt = 0; nt < 4; ++nt) {
        const int col = n0 + wn*64 + nt*16 + l15;
        bb[nt] = b2[(z+1)*512 + col];
        vb[nt] = vq[z*512 + col];
    }
    const int plane2 = plane * 2 + wn;       // 0..7
    const int gq = lane >> 4;
    #pragma unroll
    for (int mt = 0; mt < 4; ++mt)
        #pragma unroll
        for (int r = 0; r < 4; ++r) {
            float p = 0.f;
            #pragma unroll
            for (int nt = 0; nt < 4; ++nt)
                p = fmaf(fmaxf(acc[mt][nt][r] + bb[nt], 0.f), vb[nt], p);
            p += __shfl_xor(p, 1, 64);
            p += __shfl_xor(p, 2, 64);
            p += __shfl_xor(p, 4, 64);
            p += __shfl_xor(p, 8, 64);
            if (l15 == 0) {
                const int grow = r0 + wm*64 + mt*16 + gq*4 + r;
                qpart[(size_t)plane2 * 76800 + grow] = p;
            }
        }
}

// ---------------- lse: out[b] = logsumexp([q[b,0:600], zeros(100)]) ----------
__global__ void lse_kernel(const float* __restrict__ qpart, const float* __restrict__ QOFF,
                           float* __restrict__ out) {
    __shared__ float red[256];
    __shared__ float qs[QW];
    const int b = blockIdx.x, t = threadIdx.x;
    for (int k = t; k < QW; k += 256) {
        const int z = k / 100, gc = k - z * 100;
        const int grow = z * 12800 + b * 100 + gc;
        float s = QOFF[z * 128 + b];
        #pragma unroll
        for (int p = 0; p < 8; ++p) s += qpart[(size_t)p * 76800 + grow];
        qs[k] = s;
    }
    __syncthreads();
    float m = 0.0f;   // zero tail participates in the max
    for (int k = t; k < QW; k += 256) m = fmaxf(m, qs[k]);
    red[t] = m; __syncthreads();
    for (int s = 128; s > 0; s >>= 1) { if (t < s) red[t] = fmaxf(red[t], red[t+s]); __syncthreads(); }
    m = red[0]; __syncthreads();
    float sum = 0.0f;
    for (int k = t; k < QW; k += 256) sum += expf(qs[k] - m);
    red[t] = sum; __syncthreads();
    for (int s = 128; s > 0; s >>= 1) { if (t < s) red[t] += red[t+s]; __syncthreads(); }
    if (t == 0) out[b] = logf(red[0] + 100.0f * expf(-m)) + m;
}

extern "C" void kernel_launch(void* const* d_in, const int* in_sizes, int n_in,
                              void* d_out, int out_size, void* d_ws, size_t ws_size,
                              hipStream_t stream) {
    const float* obs     = (const float*)d_in[0];
    const float* actions = (const float*)d_in[1];
    const float* W1      = (const float*)d_in[2];
    const float* b1      = (const float*)d_in[3];
    const float* W2      = (const float*)d_in[4];
    const float* b2      = (const float*)d_in[5];
    const float* W3      = (const float*)d_in[6];
    const float* b3      = (const float*)d_in[7];
    const float* Wp      = (const float*)d_in[8];
    const float* bp      = (const float*)d_in[9];
    float* out = (float*)d_out;
    float* ws  = (float*)d_ws;

    // workspace layout (float offsets)
    unsigned short* obs_bf = (unsigned short*)(ws);            // 32768 f
    unsigned short* W1AT   = (unsigned short*)(ws + 32768);    // 786432 f
    unsigned short* W2T    = (unsigned short*)(ws + 819200);   // 786432 f
    unsigned short* W1Cbf  = (unsigned short*)(ws + 1605632);  // 196608 f
    unsigned short* W2bf   = (unsigned short*)(ws + 1802240);  // 786432 f
    unsigned short* W3bf   = (unsigned short*)(ws + 2588672);  // 196608 f
    float* Yobs  = ws + 2785280;                               // 393216 f
    float* QOFF  = ws + 3571712;                               // 1024 f
    float* vq    = ws + 3572736;                               // 3072 f
    float* qpart = ws + 3575808;                               // 614400 f
    unsigned short* H1 = (unsigned short*)(ws + 4190208);      // 19660800 f

    prep_kernel<<<5452, 256, 0, stream>>>(obs, W1, W2, W3, Wp,
                                          obs_bf, W1Cbf, W2bf, W3bf, W1AT, W2T, vq);
    yobs_kernel<<<dim3(2,4,6), 256, 0, stream>>>(obs_bf, W1AT, b1, Yobs);
    chain_kernel<<<BATCH, 1024, 0, stream>>>(Yobs, W1, W1Cbf, W2bf, W3bf, b2, b3, actions, Wp, bp, H1, QOFF);
    gemm2q_kernel<<<2400, 256, 0, stream>>>(H1, W2T, b2, vq, qpart);
    lse_kernel<<<BATCH, 256, 0, stream>>>(qpart, QOFF, out);
}